// Round 8
// baseline (1545.893 us; speedup 1.0000x reference)
//
#include <hip/hip_runtime.h>
#include <math.h>

// FNO1d: B=64, N=8192, F_IN=2, W=64, L=5, M=16, PAD=9 -> NLEN=8201
#define SROW 8208      // row stride (16-float aligned), >= NLEN
#define NLEN 8201
#define NB 64
#define W 64
#define M 16
#define NL 5
#define TWO_PI 6.283185307179586476925286766559

__device__ __forceinline__ float gelu_exact(float x) {
    return 0.5f * x * (1.0f + erff(x * 0.70710678118654752f));
}

// async global->LDS, 16B per lane: LDS dest = wave-uniform base + lane*16.
__device__ __forceinline__ void gld16(const float* g, float* l) {
    __builtin_amdgcn_global_load_lds(
        (const __attribute__((address_space(1))) void*)g,
        (__attribute__((address_space(3))) void*)l, 16, 0, 0);
}

// Twiddle tables cosT[k][n], sinT[k][n] (fp64-accurate) + ones/zeros rows.
__global__ void ktable(float* __restrict__ cosT, float* __restrict__ sinT,
                       float* __restrict__ onesz) {
    int n = blockIdx.x * 256 + threadIdx.x;
    int k = blockIdx.y;
    if (n >= SROW) return;
    if (k < 16) {
        long long m = ((long long)k * (long long)n) % NLEN;
        double th = (TWO_PI / (double)NLEN) * (double)m;
        double sv, cv;
        sincos(th, &sv, &cv);
        cosT[k * SROW + n] = (float)cv;
        sinT[k * SROW + n] = (float)sv;
    } else {
        onesz[(k - 16) * SROW + n] = (k == 16) ? 1.0f : 0.0f;
    }
}

// Lift: v[b][w][n] = x[b][n][:]@lift_w + lift_b, 0 in pad. 4 cols/thread, float4 I/O.
__global__ __launch_bounds__(256) void klift(const float* __restrict__ x,
        const float* __restrict__ lw, const float* __restrict__ lb,
        float* __restrict__ v) {
    int n4 = blockIdx.x * 256 + threadIdx.x;   // 2052 groups of 4 cols
    int b = blockIdx.y;
    if (n4 >= 2052) return;
    int n = n4 * 4;
    bool in = (n < 8192);      // 8192%4==0: group fully in or fully pad
    float4 xa = {0.f, 0.f, 0.f, 0.f}, xb = {0.f, 0.f, 0.f, 0.f};
    if (in) {
        const float* xp = x + ((size_t)b * 8192 + n) * 2;
        xa = *(const float4*)xp;       // x0[n],x1[n],x0[n+1],x1[n+1]
        xb = *(const float4*)(xp + 4);
    }
    float* vp = v + (size_t)b * W * SROW + n;
    #pragma unroll
    for (int w = 0; w < W; w++) {
        float4 o4 = {0.f, 0.f, 0.f, 0.f};
        if (in) {
            float l0 = lw[w], l1 = lw[W + w], bb = lb[w];
            o4.x = fmaf(xa.x, l0, fmaf(xa.y, l1, bb));
            o4.y = fmaf(xa.z, l0, fmaf(xa.w, l1, bb));
            o4.z = fmaf(xb.x, l0, fmaf(xb.y, l1, bb));
            o4.w = fmaf(xb.z, l0, fmaf(xb.w, l1, bb));
        }
        *(float4*)(vp + (size_t)w * SROW) = o4;
    }
}

// Forward DFT, 16 modes. 2 rows/block (2048 blocks), unroll-2 chunks for ILP.
// acc = 2*16*2 = 64 regs; twiddles via k-recurrence from table row k=1.
__global__ __launch_bounds__(256) void kdft(const float* __restrict__ v,
        const float* __restrict__ cosT, const float* __restrict__ sinT,
        float* __restrict__ F) {
    int row0 = blockIdx.x * 2;
    int t = threadIdx.x;
    float accR[2][16], accI[2][16];
    #pragma unroll
    for (int r = 0; r < 2; r++)
        #pragma unroll
        for (int k = 0; k < 16; k++) { accR[r][k] = 0.f; accI[r][k] = 0.f; }
    const float* v0 = v + (size_t)row0 * SROW;

    #pragma unroll
    for (int i = 0; i < 4; i++) {
        int nA = (t + i * 512) << 2;         // chunks A and B, independent
        int nB = nA + 1024;
        float4 c1A = *(const float4*)(cosT + SROW + nA);
        float4 s1A = *(const float4*)(sinT + SROW + nA);
        float4 vA0 = *(const float4*)(v0 + nA);
        float4 vA1 = *(const float4*)(v0 + SROW + nA);
        float4 c1B = *(const float4*)(cosT + SROW + nB);
        float4 s1B = *(const float4*)(sinT + SROW + nB);
        float4 vB0 = *(const float4*)(v0 + nB);
        float4 vB1 = *(const float4*)(v0 + SROW + nB);

        accR[0][0] += (vA0.x + vA0.y) + (vA0.z + vA0.w);
        accR[1][0] += (vA1.x + vA1.y) + (vA1.z + vA1.w);
        float4 ck = c1A, sk = s1A;
        #pragma unroll
        for (int k = 1; k < 16; k++) {
            float a0 = accR[0][k];
            a0 = fmaf(vA0.x, ck.x, a0); a0 = fmaf(vA0.y, ck.y, a0);
            a0 = fmaf(vA0.z, ck.z, a0); a0 = fmaf(vA0.w, ck.w, a0);
            accR[0][k] = a0;
            float b0 = accI[0][k];
            b0 = fmaf(-vA0.x, sk.x, b0); b0 = fmaf(-vA0.y, sk.y, b0);
            b0 = fmaf(-vA0.z, sk.z, b0); b0 = fmaf(-vA0.w, sk.w, b0);
            accI[0][k] = b0;
            float a1 = accR[1][k];
            a1 = fmaf(vA1.x, ck.x, a1); a1 = fmaf(vA1.y, ck.y, a1);
            a1 = fmaf(vA1.z, ck.z, a1); a1 = fmaf(vA1.w, ck.w, a1);
            accR[1][k] = a1;
            float b1 = accI[1][k];
            b1 = fmaf(-vA1.x, sk.x, b1); b1 = fmaf(-vA1.y, sk.y, b1);
            b1 = fmaf(-vA1.z, sk.z, b1); b1 = fmaf(-vA1.w, sk.w, b1);
            accI[1][k] = b1;
            if (k < 15) {
                float4 cn, sn;
                cn.x = fmaf(ck.x, c1A.x, -sk.x * s1A.x); sn.x = fmaf(ck.x, s1A.x, sk.x * c1A.x);
                cn.y = fmaf(ck.y, c1A.y, -sk.y * s1A.y); sn.y = fmaf(ck.y, s1A.y, sk.y * c1A.y);
                cn.z = fmaf(ck.z, c1A.z, -sk.z * s1A.z); sn.z = fmaf(ck.z, s1A.z, sk.z * c1A.z);
                cn.w = fmaf(ck.w, c1A.w, -sk.w * s1A.w); sn.w = fmaf(ck.w, s1A.w, sk.w * c1A.w);
                ck = cn; sk = sn;
            }
        }
        accR[0][0] += (vB0.x + vB0.y) + (vB0.z + vB0.w);
        accR[1][0] += (vB1.x + vB1.y) + (vB1.z + vB1.w);
        ck = c1B; sk = s1B;
        #pragma unroll
        for (int k = 1; k < 16; k++) {
            float a0 = accR[0][k];
            a0 = fmaf(vB0.x, ck.x, a0); a0 = fmaf(vB0.y, ck.y, a0);
            a0 = fmaf(vB0.z, ck.z, a0); a0 = fmaf(vB0.w, ck.w, a0);
            accR[0][k] = a0;
            float b0 = accI[0][k];
            b0 = fmaf(-vB0.x, sk.x, b0); b0 = fmaf(-vB0.y, sk.y, b0);
            b0 = fmaf(-vB0.z, sk.z, b0); b0 = fmaf(-vB0.w, sk.w, b0);
            accI[0][k] = b0;
            float a1 = accR[1][k];
            a1 = fmaf(vB1.x, ck.x, a1); a1 = fmaf(vB1.y, ck.y, a1);
            a1 = fmaf(vB1.z, ck.z, a1); a1 = fmaf(vB1.w, ck.w, a1);
            accR[1][k] = a1;
            float b1 = accI[1][k];
            b1 = fmaf(-vB1.x, sk.x, b1); b1 = fmaf(-vB1.y, sk.y, b1);
            b1 = fmaf(-vB1.z, sk.z, b1); b1 = fmaf(-vB1.w, sk.w, b1);
            accI[1][k] = b1;
            if (k < 15) {
                float4 cn, sn;
                cn.x = fmaf(ck.x, c1B.x, -sk.x * s1B.x); sn.x = fmaf(ck.x, s1B.x, sk.x * c1B.x);
                cn.y = fmaf(ck.y, c1B.y, -sk.y * s1B.y); sn.y = fmaf(ck.y, s1B.y, sk.y * c1B.y);
                cn.z = fmaf(ck.z, c1B.z, -sk.z * s1B.z); sn.z = fmaf(ck.z, s1B.z, sk.z * c1B.z);
                cn.w = fmaf(ck.w, c1B.w, -sk.w * s1B.w); sn.w = fmaf(ck.w, s1B.w, sk.w * c1B.w);
                ck = cn; sk = sn;
            }
        }
    }

    // tails: c=2048,2049 (n=8192..8199, pad positions evolve nonzero after layer 1),
    // plus the single n=8200.
    if (t < 2) {
        int n = 8192 + t * 4;
        float4 vv0 = *(const float4*)(v0 + n);
        float4 vv1 = *(const float4*)(v0 + SROW + n);
        #pragma unroll
        for (int k = 0; k < 16; k++) {
            float4 cc = *(const float4*)(cosT + (size_t)k * SROW + n);
            float4 ss = *(const float4*)(sinT + (size_t)k * SROW + n);
            float a0 = accR[0][k], b0 = accI[0][k];
            a0 = fmaf(vv0.x, cc.x, a0); a0 = fmaf(vv0.y, cc.y, a0);
            a0 = fmaf(vv0.z, cc.z, a0); a0 = fmaf(vv0.w, cc.w, a0);
            b0 = fmaf(-vv0.x, ss.x, b0); b0 = fmaf(-vv0.y, ss.y, b0);
            b0 = fmaf(-vv0.z, ss.z, b0); b0 = fmaf(-vv0.w, ss.w, b0);
            accR[0][k] = a0; accI[0][k] = b0;
            float a1 = accR[1][k], b1 = accI[1][k];
            a1 = fmaf(vv1.x, cc.x, a1); a1 = fmaf(vv1.y, cc.y, a1);
            a1 = fmaf(vv1.z, cc.z, a1); a1 = fmaf(vv1.w, cc.w, a1);
            b1 = fmaf(-vv1.x, ss.x, b1); b1 = fmaf(-vv1.y, ss.y, b1);
            b1 = fmaf(-vv1.z, ss.z, b1); b1 = fmaf(-vv1.w, ss.w, b1);
            accR[1][k] = a1; accI[1][k] = b1;
        }
    }
    if (t == 2) {
        int n = 8200;
        #pragma unroll
        for (int k = 0; k < 16; k++) {
            float cv = cosT[(size_t)k * SROW + n], sv = sinT[(size_t)k * SROW + n];
            float v0r = v0[n], v1r = v0[SROW + n];
            accR[0][k] = fmaf(v0r, cv, accR[0][k]);
            accI[0][k] = fmaf(-v0r, sv, accI[0][k]);
            accR[1][k] = fmaf(v1r, cv, accR[1][k]);
            accI[1][k] = fmaf(-v1r, sv, accI[1][k]);
        }
    }

    #pragma unroll
    for (int r = 0; r < 2; r++)
        #pragma unroll
        for (int k = 0; k < 16; k++) {
            float xr = accR[r][k], xi = accI[r][k];
            #pragma unroll
            for (int off = 32; off > 0; off >>= 1) {
                xr += __shfl_down(xr, off, 64);
                xi += __shfl_down(xi, off, 64);
            }
            accR[r][k] = xr; accI[r][k] = xi;
        }
    __shared__ float red[4][64];
    int lane = t & 63, wv = t >> 6;
    if (lane == 0) {
        #pragma unroll
        for (int r = 0; r < 2; r++)
            #pragma unroll
            for (int k = 0; k < 16; k++) {
                red[wv][r * 32 + 2 * k]     = accR[r][k];
                red[wv][r * 32 + 2 * k + 1] = accI[r][k];
            }
    }
    __syncthreads();
    if (t < 64) {
        float sum = red[0][t] + red[1][t] + red[2][t] + red[3][t];
        int r = t >> 5, rem = t & 31, k = rem >> 1, comp = rem & 1;
        F[(((size_t)(row0 + r)) * M + k) * 2 + comp] = sum;
    }
}

// Mode mix + weight build (kprep merged). Block (b,kg) owns k in [4kg,4kg+4)
// for all o: computes Pm and writes its Wf rows directly; also copies 16 cw rows.
// Wf[b][96][64]: k<64 cw; 64..78 +PmR(1..15)*2/N; 79..93 -PmI(1..15)*2/N;
// 94 cb+PmR(0)/N; 95 zero.
__global__ __launch_bounds__(256) void kmix(const float* __restrict__ F,
        const float* __restrict__ kr, const float* __restrict__ ki,
        const float* __restrict__ cw, const float* __restrict__ cb,
        float* __restrict__ Wf, int l) {
    int b = blockIdx.x, kg = blockIdx.y;
    int t = threadIdx.x;
    int o = t & 63, ii = t >> 6;   // 4 i-groups of 16
    const float* fb = F + (size_t)b * W * M * 2;
    const float* krl = kr + (size_t)l * W * W * M;
    const float* kil = ki + (size_t)l * W * W * M;
    float* wb = Wf + (size_t)b * 96 * 64;
    float pr[4] = {0.f, 0.f, 0.f, 0.f}, pi[4] = {0.f, 0.f, 0.f, 0.f};
    for (int i = ii * 16; i < ii * 16 + 16; i++) {
        float4 kr4 = *(const float4*)(krl + ((size_t)i * W + o) * M + kg * 4);
        float4 ki4 = *(const float4*)(kil + ((size_t)i * W + o) * M + kg * 4);
        float4 f0 = *(const float4*)(fb + ((size_t)i * M + kg * 4) * 2);
        float4 f1 = *(const float4*)(fb + ((size_t)i * M + kg * 4) * 2 + 4);
        pr[0] += f0.x * kr4.x - f0.y * ki4.x;  pi[0] += f0.x * ki4.x + f0.y * kr4.x;
        pr[1] += f0.z * kr4.y - f0.w * ki4.y;  pi[1] += f0.z * ki4.y + f0.w * kr4.y;
        pr[2] += f1.x * kr4.z - f1.y * ki4.z;  pi[2] += f1.x * ki4.z + f1.y * kr4.z;
        pr[3] += f1.z * kr4.w - f1.w * ki4.w;  pi[3] += f1.z * ki4.w + f1.w * kr4.w;
    }
    // copy this block's 16 cw rows: k in [16kg, 16kg+16)
    const float* cwl = cw + (size_t)l * W * W;
    #pragma unroll
    for (int it = 0; it < 4; it++) {
        int idx = t + it * 256;
        int krow = 16 * kg + (idx >> 6), oo = idx & 63;
        wb[krow * 64 + oo] = cwl[oo * 64 + krow];
    }
    __shared__ float red[4][64][8];
    #pragma unroll
    for (int c = 0; c < 4; c++) {
        red[ii][o][2 * c]     = pr[c];
        red[ii][o][2 * c + 1] = pi[c];
    }
    __syncthreads();
    if (ii == 0) {
        #pragma unroll
        for (int c = 0; c < 4; c++) {
            int k = kg * 4 + c;
            float sr = red[0][o][2 * c] + red[1][o][2 * c] + red[2][o][2 * c] + red[3][o][2 * c];
            float si = red[0][o][2 * c + 1] + red[1][o][2 * c + 1] + red[2][o][2 * c + 1] + red[3][o][2 * c + 1];
            if (k == 0) {
                wb[94 * 64 + o] = cb[l * W + o] + sr * (1.0f / (float)NLEN);
                wb[95 * 64 + o] = 0.f;
            } else {
                wb[(63 + k) * 64 + o] = sr * (2.0f / (float)NLEN);
                wb[(78 + k) * 64 + o] = -si * (2.0f / (float)NLEN);
            }
        }
    }
}

// Fused conv + inverse transform + gelu, IN-PLACE. 512 threads = 8 waves.
// Wave w owns o rows [8w,8w+8); block covers 64o x 256n. Thread: 8o x 4n.
// Weights read wave-uniformly from global Wf -> s_load (scalar pipe).
__global__ __launch_bounds__(512, 6) void kconv(float* v,
        const float* __restrict__ Wf, const float* __restrict__ cosT,
        const float* __restrict__ sinT, const float* __restrict__ onesz) {
    __shared__ __align__(16) float U[2][12][256];
    int t = threadIdx.x;
    int b = blockIdx.y;
    int n0 = blockIdx.x * 256;
    int lane = t & 63;
    int wvu = __builtin_amdgcn_readfirstlane(t >> 6);   // 0..7, provably uniform
    const float* vb = v + (size_t)b * (W * SROW);
    const float* Wb = Wf + (size_t)b * (96 * 64) + wvu * 8;
    int colf = n0 + lane * 4;

    // stage chunk 0 (rows 0..11, all v rows)
    gld16(vb + (size_t)wvu * SROW + colf, &U[0][wvu][0]);
    if (wvu < 4) gld16(vb + (size_t)(8 + wvu) * SROW + colf, &U[0][8 + wvu][0]);

    float acc[8][4];
    #pragma unroll
    for (int r = 0; r < 8; r++) { acc[r][0] = acc[r][1] = acc[r][2] = acc[r][3] = 0.f; }
    __syncthreads();

    int buf = 0;
    for (int c = 0; c < 8; c++) {
        if (c < 7) {
            int k0 = (c + 1) * 12;
            int r0 = k0 + wvu;
            const float* s0 = (r0 < 64) ? vb + (size_t)r0 * SROW
                            : (r0 < 79) ? cosT + (size_t)(r0 - 63) * SROW
                            : (r0 < 94) ? sinT + (size_t)(r0 - 78) * SROW
                            : onesz + (size_t)(r0 - 94) * SROW;
            gld16(s0 + colf, &U[buf ^ 1][wvu][0]);
            if (wvu < 4) {
                int r1 = k0 + 8 + wvu;
                const float* s1 = (r1 < 64) ? vb + (size_t)r1 * SROW
                                : (r1 < 79) ? cosT + (size_t)(r1 - 63) * SROW
                                : (r1 < 94) ? sinT + (size_t)(r1 - 78) * SROW
                                : onesz + (size_t)(r1 - 94) * SROW;
                gld16(s1 + colf, &U[buf ^ 1][8 + wvu][0]);
            }
        }
        #pragma unroll
        for (int kk = 0; kk < 12; kk++) {
            int k = c * 12 + kk;
            float4 u = *(const float4*)&U[buf][kk][lane * 4];
            const float* wk = Wb + k * 64;          // wave-uniform -> s_load
            #pragma unroll
            for (int r = 0; r < 8; r++) {
                float wr = wk[r];
                acc[r][0] = fmaf(wr, u.x, acc[r][0]);
                acc[r][1] = fmaf(wr, u.y, acc[r][1]);
                acc[r][2] = fmaf(wr, u.z, acc[r][2]);
                acc[r][3] = fmaf(wr, u.w, acc[r][3]);
            }
        }
        if (c < 7) { __syncthreads(); buf ^= 1; }
    }

    if (colf < SROW) {
        float* vo = v + (size_t)b * (W * SROW) + colf;
        #pragma unroll
        for (int r = 0; r < 8; r++) {
            float4 o4;
            o4.x = gelu_exact(acc[r][0]);
            o4.y = gelu_exact(acc[r][1]);
            o4.z = gelu_exact(acc[r][2]);
            o4.w = gelu_exact(acc[r][3]);
            *(float4*)(vo + (size_t)(wvu * 8 + r) * SROW) = o4;
        }
    }
}

// Final projection: 1024 threads = 16 waves; wave w owns h rows [8w,8w+8)
// (weights wave-uniform -> s_load); thread tile 8h x 4n (acc=32 regs, no spill).
__global__ __launch_bounds__(1024, 4) void kproj(const float* __restrict__ v,
        const float* __restrict__ w1, const float* __restrict__ b1,
        const float* __restrict__ w2, const float* __restrict__ b2,
        float* __restrict__ out) {
    __shared__ __align__(16) float U[2][8][256];     // 16 KB
    __shared__ __align__(16) float red[16][256];     // 16 KB
    int t = threadIdx.x;
    int b = blockIdx.y;
    int n0 = blockIdx.x * 256;   // 32 blocks x 256 = 8192 exact
    int lane = t & 63;
    int wvu = __builtin_amdgcn_readfirstlane(t >> 6);   // 0..15
    const float* vb = v + (size_t)b * (W * SROW);
    int colf = n0 + lane * 4;
    int h0 = wvu * 8;

    if (wvu < 8) gld16(vb + (size_t)wvu * SROW + colf, &U[0][wvu][0]);

    float acc[8][4];
    #pragma unroll
    for (int r = 0; r < 8; r++) {
        float bs = b1[h0 + r];                      // uniform -> s_load
        acc[r][0] = acc[r][1] = acc[r][2] = acc[r][3] = bs;
    }
    __syncthreads();

    int buf = 0;
    for (int c = 0; c < 8; c++) {
        if (c < 7 && wvu < 8)
            gld16(vb + (size_t)((c + 1) * 8 + wvu) * SROW + colf, &U[buf ^ 1][wvu][0]);
        #pragma unroll
        for (int kk = 0; kk < 8; kk++) {
            int k = c * 8 + kk;
            float4 u = *(const float4*)&U[buf][kk][lane * 4];
            const float* wk = w1 + k * 128 + h0;    // uniform -> s_load
            #pragma unroll
            for (int r = 0; r < 8; r++) {
                float wr = wk[r];
                acc[r][0] = fmaf(wr, u.x, acc[r][0]);
                acc[r][1] = fmaf(wr, u.y, acc[r][1]);
                acc[r][2] = fmaf(wr, u.z, acc[r][2]);
                acc[r][3] = fmaf(wr, u.w, acc[r][3]);
            }
        }
        if (c < 7) { __syncthreads(); buf ^= 1; }
    }

    float p0 = 0.f, p1 = 0.f, p2 = 0.f, p3 = 0.f;
    #pragma unroll
    for (int r = 0; r < 8; r++) {
        float wh = w2[h0 + r];                      // uniform -> s_load
        p0 = fmaf(gelu_exact(acc[r][0]), wh, p0);
        p1 = fmaf(gelu_exact(acc[r][1]), wh, p1);
        p2 = fmaf(gelu_exact(acc[r][2]), wh, p2);
        p3 = fmaf(gelu_exact(acc[r][3]), wh, p3);
    }
    float4 p4 = {p0, p1, p2, p3};
    *(float4*)&red[wvu][lane * 4] = p4;
    __syncthreads();
    if (t < 256) {
        float s = b2[0];
        #pragma unroll
        for (int w = 0; w < 16; w++) s += red[w][t];
        out[(size_t)b * 8192 + n0 + t] = s;
    }
}

extern "C" void kernel_launch(void* const* d_in, const int* in_sizes, int n_in,
                              void* d_out, int out_size, void* d_ws, size_t ws_size,
                              hipStream_t stream) {
    const float* x  = (const float*)d_in[0];
    const float* lw = (const float*)d_in[1];
    const float* lb = (const float*)d_in[2];
    const float* kr = (const float*)d_in[3];
    const float* ki = (const float*)d_in[4];
    const float* cw = (const float*)d_in[5];
    const float* cb = (const float*)d_in[6];
    const float* w1 = (const float*)d_in[7];
    const float* b1 = (const float*)d_in[8];
    const float* w2 = (const float*)d_in[9];
    const float* b2 = (const float*)d_in[10];
    float* out = (float*)d_out;

    // workspace (floats): v 33,619,968 | cosT/sinT 131,328 ea | onesz 24,624 |
    // F 131,072 | Wf 393,216  => ~137.8 MB
    float* ws = (float*)d_ws;
    size_t vsz = (size_t)NB * W * SROW;
    float* v     = ws;
    float* cosT  = v + vsz;
    float* sinT  = cosT + (size_t)16 * SROW;
    float* onesz = sinT + (size_t)16 * SROW;
    float* F     = onesz + (size_t)3 * SROW;
    float* Wf    = F + (size_t)NB * W * M * 2;

    ktable<<<dim3(33, 18), 256, 0, stream>>>(cosT, sinT, onesz);
    klift<<<dim3(9, NB), 256, 0, stream>>>(x, lw, lb, v);

    for (int l = 0; l < NL; l++) {
        kdft<<<NB * W / 2, 256, 0, stream>>>(v, cosT, sinT, F);
        kmix<<<dim3(NB, 4), 256, 0, stream>>>(F, kr, ki, cw, cb, Wf, l);
        kconv<<<dim3(33, NB), 512, 0, stream>>>(v, Wf, cosT, sinT, onesz);
    }
    kproj<<<dim3(32, NB), 1024, 0, stream>>>(v, w1, b1, w2, b2, out);
}

// Round 9
// 1371.382 us; speedup vs baseline: 1.1273x; 1.1273x over previous
//
#include <hip/hip_runtime.h>
#include <math.h>

// FNO1d: B=64, N=8192, F_IN=2, W=64, L=5, M=16, PAD=9 -> NLEN=8201
#define SROW 8208      // row stride (16-float aligned), >= NLEN
#define NLEN 8201
#define NB 64
#define W 64
#define M 16
#define NL 5
#define TWO_PI 6.283185307179586476925286766559

__device__ __forceinline__ float gelu_exact(float x) {
    return 0.5f * x * (1.0f + erff(x * 0.70710678118654752f));
}

// async global->LDS, 16B per lane: LDS dest = wave-uniform base + lane*16.
__device__ __forceinline__ void gld16(const float* g, float* l) {
    __builtin_amdgcn_global_load_lds(
        (const __attribute__((address_space(1))) void*)g,
        (__attribute__((address_space(3))) void*)l, 16, 0, 0);
}

// Twiddle tables cosT[k][n], sinT[k][n] (fp64-accurate) + ones/zeros rows.
__global__ void ktable(float* __restrict__ cosT, float* __restrict__ sinT,
                       float* __restrict__ onesz) {
    int n = blockIdx.x * 256 + threadIdx.x;
    int k = blockIdx.y;
    if (n >= SROW) return;
    if (k < 16) {
        long long m = ((long long)k * (long long)n) % NLEN;
        double th = (TWO_PI / (double)NLEN) * (double)m;
        double sv, cv;
        sincos(th, &sv, &cv);
        cosT[k * SROW + n] = (float)cv;
        sinT[k * SROW + n] = (float)sv;
    } else {
        onesz[(k - 16) * SROW + n] = (k == 16) ? 1.0f : 0.0f;
    }
}

// Lift: v[b][w][n] = x[b][n][:]@lift_w + lift_b, 0 in pad. 4 cols/thread, float4 I/O.
__global__ __launch_bounds__(256) void klift(const float* __restrict__ x,
        const float* __restrict__ lw, const float* __restrict__ lb,
        float* __restrict__ v) {
    int n4 = blockIdx.x * 256 + threadIdx.x;   // 2052 groups of 4 cols
    int b = blockIdx.y;
    if (n4 >= 2052) return;
    int n = n4 * 4;
    bool in = (n < 8192);      // 8192%4==0: group fully in or fully pad
    float4 xa = {0.f, 0.f, 0.f, 0.f}, xb = {0.f, 0.f, 0.f, 0.f};
    if (in) {
        const float* xp = x + ((size_t)b * 8192 + n) * 2;
        xa = *(const float4*)xp;       // x0[n],x1[n],x0[n+1],x1[n+1]
        xb = *(const float4*)(xp + 4);
    }
    float* vp = v + (size_t)b * W * SROW + n;
    #pragma unroll
    for (int w = 0; w < W; w++) {
        float4 o4 = {0.f, 0.f, 0.f, 0.f};
        if (in) {
            float l0 = lw[w], l1 = lw[W + w], bb = lb[w];
            o4.x = fmaf(xa.x, l0, fmaf(xa.y, l1, bb));
            o4.y = fmaf(xa.z, l0, fmaf(xa.w, l1, bb));
            o4.z = fmaf(xb.x, l0, fmaf(xb.y, l1, bb));
            o4.w = fmaf(xb.z, l0, fmaf(xb.w, l1, bb));
        }
        *(float4*)(vp + (size_t)w * SROW) = o4;
    }
}

// Forward DFT, 16 modes. 2 rows/block (2048 blocks), LOW-VGPR strided loop:
// acc = 64 regs; 4 independent float4 loads/iter; twiddles via k-recurrence.
// Latency hidden by wave count (~5 waves/SIMD), not manual unrolling.
__global__ __launch_bounds__(256) void kdft(const float* __restrict__ v,
        const float* __restrict__ cosT, const float* __restrict__ sinT,
        float* __restrict__ F) {
    int row0 = blockIdx.x * 2;
    int t = threadIdx.x;
    float accR[2][16], accI[2][16];
    #pragma unroll
    for (int r = 0; r < 2; r++)
        #pragma unroll
        for (int k = 0; k < 16; k++) { accR[r][k] = 0.f; accI[r][k] = 0.f; }
    const float* v0 = v + (size_t)row0 * SROW;

    for (int c = t; c < 2050; c += 256) {   // n = 4c..4c+3, covers n<8200
        int n = c << 2;
        float4 c1 = *(const float4*)(cosT + SROW + n);
        float4 s1 = *(const float4*)(sinT + SROW + n);
        float4 va = *(const float4*)(v0 + n);
        float4 vb = *(const float4*)(v0 + SROW + n);
        accR[0][0] += (va.x + va.y) + (va.z + va.w);
        accR[1][0] += (vb.x + vb.y) + (vb.z + vb.w);
        float4 ck = c1, sk = s1;
        #pragma unroll
        for (int k = 1; k < 16; k++) {
            float a0 = accR[0][k];
            a0 = fmaf(va.x, ck.x, a0); a0 = fmaf(va.y, ck.y, a0);
            a0 = fmaf(va.z, ck.z, a0); a0 = fmaf(va.w, ck.w, a0);
            accR[0][k] = a0;
            float b0 = accI[0][k];
            b0 = fmaf(-va.x, sk.x, b0); b0 = fmaf(-va.y, sk.y, b0);
            b0 = fmaf(-va.z, sk.z, b0); b0 = fmaf(-va.w, sk.w, b0);
            accI[0][k] = b0;
            float a1 = accR[1][k];
            a1 = fmaf(vb.x, ck.x, a1); a1 = fmaf(vb.y, ck.y, a1);
            a1 = fmaf(vb.z, ck.z, a1); a1 = fmaf(vb.w, ck.w, a1);
            accR[1][k] = a1;
            float b1 = accI[1][k];
            b1 = fmaf(-vb.x, sk.x, b1); b1 = fmaf(-vb.y, sk.y, b1);
            b1 = fmaf(-vb.z, sk.z, b1); b1 = fmaf(-vb.w, sk.w, b1);
            accI[1][k] = b1;
            if (k < 15) {
                float4 cn, sn;
                cn.x = fmaf(ck.x, c1.x, -sk.x * s1.x); sn.x = fmaf(ck.x, s1.x, sk.x * c1.x);
                cn.y = fmaf(ck.y, c1.y, -sk.y * s1.y); sn.y = fmaf(ck.y, s1.y, sk.y * c1.y);
                cn.z = fmaf(ck.z, c1.z, -sk.z * s1.z); sn.z = fmaf(ck.z, s1.z, sk.z * c1.z);
                cn.w = fmaf(ck.w, c1.w, -sk.w * s1.w); sn.w = fmaf(ck.w, s1.w, sk.w * c1.w);
                ck = cn; sk = sn;
            }
        }
    }

    if (t == 0) {        // tail n = 8200 (pad cols beyond 8200 are never read)
        int n = 8200;
        #pragma unroll
        for (int k = 0; k < 16; k++) {
            float cv = cosT[(size_t)k * SROW + n], sv = sinT[(size_t)k * SROW + n];
            float v0r = v0[n], v1r = v0[SROW + n];
            accR[0][k] = fmaf(v0r, cv, accR[0][k]);
            accI[0][k] = fmaf(-v0r, sv, accI[0][k]);
            accR[1][k] = fmaf(v1r, cv, accR[1][k]);
            accI[1][k] = fmaf(-v1r, sv, accI[1][k]);
        }
    }

    #pragma unroll
    for (int r = 0; r < 2; r++)
        #pragma unroll
        for (int k = 0; k < 16; k++) {
            float xr = accR[r][k], xi = accI[r][k];
            #pragma unroll
            for (int off = 32; off > 0; off >>= 1) {
                xr += __shfl_down(xr, off, 64);
                xi += __shfl_down(xi, off, 64);
            }
            accR[r][k] = xr; accI[r][k] = xi;
        }
    __shared__ float red[4][64];
    int lane = t & 63, wv = t >> 6;
    if (lane == 0) {
        #pragma unroll
        for (int r = 0; r < 2; r++)
            #pragma unroll
            for (int k = 0; k < 16; k++) {
                red[wv][r * 32 + 2 * k]     = accR[r][k];
                red[wv][r * 32 + 2 * k + 1] = accI[r][k];
            }
    }
    __syncthreads();
    if (t < 64) {
        float sum = red[0][t] + red[1][t] + red[2][t] + red[3][t];
        int r = t >> 5, rem = t & 31, k = rem >> 1, comp = rem & 1;
        F[(((size_t)(row0 + r)) * M + k) * 2 + comp] = sum;
    }
}

// Mode mix + weight build (kprep merged). Block (b,kg) owns k in [4kg,4kg+4)
// for all o: computes Pm and writes its Wf rows directly; also copies 16 cw rows.
// Wf[b][96][64]: k<64 cw; 64..78 +PmR(1..15)*2/N; 79..93 -PmI(1..15)*2/N;
// 94 cb+PmR(0)/N; 95 zero.
__global__ __launch_bounds__(256) void kmix(const float* __restrict__ F,
        const float* __restrict__ kr, const float* __restrict__ ki,
        const float* __restrict__ cw, const float* __restrict__ cb,
        float* __restrict__ Wf, int l) {
    int b = blockIdx.x, kg = blockIdx.y;
    int t = threadIdx.x;
    int o = t & 63, ii = t >> 6;   // 4 i-groups of 16
    const float* fb = F + (size_t)b * W * M * 2;
    const float* krl = kr + (size_t)l * W * W * M;
    const float* kil = ki + (size_t)l * W * W * M;
    float* wb = Wf + (size_t)b * 96 * 64;
    float pr[4] = {0.f, 0.f, 0.f, 0.f}, pi[4] = {0.f, 0.f, 0.f, 0.f};
    for (int i = ii * 16; i < ii * 16 + 16; i++) {
        float4 kr4 = *(const float4*)(krl + ((size_t)i * W + o) * M + kg * 4);
        float4 ki4 = *(const float4*)(kil + ((size_t)i * W + o) * M + kg * 4);
        float4 f0 = *(const float4*)(fb + ((size_t)i * M + kg * 4) * 2);
        float4 f1 = *(const float4*)(fb + ((size_t)i * M + kg * 4) * 2 + 4);
        pr[0] += f0.x * kr4.x - f0.y * ki4.x;  pi[0] += f0.x * ki4.x + f0.y * kr4.x;
        pr[1] += f0.z * kr4.y - f0.w * ki4.y;  pi[1] += f0.z * ki4.y + f0.w * kr4.y;
        pr[2] += f1.x * kr4.z - f1.y * ki4.z;  pi[2] += f1.x * ki4.z + f1.y * kr4.z;
        pr[3] += f1.z * kr4.w - f1.w * ki4.w;  pi[3] += f1.z * ki4.w + f1.w * kr4.w;
    }
    // copy this block's 16 cw rows: k in [16kg, 16kg+16)
    const float* cwl = cw + (size_t)l * W * W;
    #pragma unroll
    for (int it = 0; it < 4; it++) {
        int idx = t + it * 256;
        int krow = 16 * kg + (idx >> 6), oo = idx & 63;
        wb[krow * 64 + oo] = cwl[oo * 64 + krow];
    }
    __shared__ float red[4][64][8];
    #pragma unroll
    for (int c = 0; c < 4; c++) {
        red[ii][o][2 * c]     = pr[c];
        red[ii][o][2 * c + 1] = pi[c];
    }
    __syncthreads();
    if (ii == 0) {
        #pragma unroll
        for (int c = 0; c < 4; c++) {
            int k = kg * 4 + c;
            float sr = red[0][o][2 * c] + red[1][o][2 * c] + red[2][o][2 * c] + red[3][o][2 * c];
            float si = red[0][o][2 * c + 1] + red[1][o][2 * c + 1] + red[2][o][2 * c + 1] + red[3][o][2 * c + 1];
            if (k == 0) {
                wb[94 * 64 + o] = cb[l * W + o] + sr * (1.0f / (float)NLEN);
                wb[95 * 64 + o] = 0.f;
            } else {
                wb[(63 + k) * 64 + o] = sr * (2.0f / (float)NLEN);
                wb[(78 + k) * 64 + o] = -si * (2.0f / (float)NLEN);
            }
        }
    }
}

// Fused conv + inverse transform + gelu, IN-PLACE. 512 threads = 8 waves.
// Wave w owns o rows [8w,8w+8); block covers 64o x 256n. Thread: 8o x 4n.
// Weights read wave-uniformly from global Wf -> s_load (scalar pipe).
__global__ __launch_bounds__(512, 6) void kconv(float* v,
        const float* __restrict__ Wf, const float* __restrict__ cosT,
        const float* __restrict__ sinT, const float* __restrict__ onesz) {
    __shared__ __align__(16) float U[2][12][256];
    int t = threadIdx.x;
    int b = blockIdx.y;
    int n0 = blockIdx.x * 256;
    int lane = t & 63;
    int wvu = __builtin_amdgcn_readfirstlane(t >> 6);   // 0..7, provably uniform
    const float* vb = v + (size_t)b * (W * SROW);
    const float* Wb = Wf + (size_t)b * (96 * 64) + wvu * 8;
    int colf = n0 + lane * 4;

    // stage chunk 0 (rows 0..11, all v rows)
    gld16(vb + (size_t)wvu * SROW + colf, &U[0][wvu][0]);
    if (wvu < 4) gld16(vb + (size_t)(8 + wvu) * SROW + colf, &U[0][8 + wvu][0]);

    float acc[8][4];
    #pragma unroll
    for (int r = 0; r < 8; r++) { acc[r][0] = acc[r][1] = acc[r][2] = acc[r][3] = 0.f; }
    __syncthreads();

    int buf = 0;
    for (int c = 0; c < 8; c++) {
        if (c < 7) {
            int k0 = (c + 1) * 12;
            int r0 = k0 + wvu;
            const float* s0 = (r0 < 64) ? vb + (size_t)r0 * SROW
                            : (r0 < 79) ? cosT + (size_t)(r0 - 63) * SROW
                            : (r0 < 94) ? sinT + (size_t)(r0 - 78) * SROW
                            : onesz + (size_t)(r0 - 94) * SROW;
            gld16(s0 + colf, &U[buf ^ 1][wvu][0]);
            if (wvu < 4) {
                int r1 = k0 + 8 + wvu;
                const float* s1 = (r1 < 64) ? vb + (size_t)r1 * SROW
                                : (r1 < 79) ? cosT + (size_t)(r1 - 63) * SROW
                                : (r1 < 94) ? sinT + (size_t)(r1 - 78) * SROW
                                : onesz + (size_t)(r1 - 94) * SROW;
                gld16(s1 + colf, &U[buf ^ 1][8 + wvu][0]);
            }
        }
        #pragma unroll
        for (int kk = 0; kk < 12; kk++) {
            int k = c * 12 + kk;
            float4 u = *(const float4*)&U[buf][kk][lane * 4];
            const float* wk = Wb + k * 64;          // wave-uniform -> s_load
            #pragma unroll
            for (int r = 0; r < 8; r++) {
                float wr = wk[r];
                acc[r][0] = fmaf(wr, u.x, acc[r][0]);
                acc[r][1] = fmaf(wr, u.y, acc[r][1]);
                acc[r][2] = fmaf(wr, u.z, acc[r][2]);
                acc[r][3] = fmaf(wr, u.w, acc[r][3]);
            }
        }
        if (c < 7) { __syncthreads(); buf ^= 1; }
    }

    if (colf < SROW) {
        float* vo = v + (size_t)b * (W * SROW) + colf;
        #pragma unroll
        for (int r = 0; r < 8; r++) {
            float4 o4;
            o4.x = gelu_exact(acc[r][0]);
            o4.y = gelu_exact(acc[r][1]);
            o4.z = gelu_exact(acc[r][2]);
            o4.w = gelu_exact(acc[r][3]);
            *(float4*)(vo + (size_t)(wvu * 8 + r) * SROW) = o4;
        }
    }
}

// Final projection: 1024 threads = 16 waves; wave w owns h rows [8w,8w+8)
// (weights wave-uniform -> s_load); thread tile 8h x 4n (acc=32 regs, no spill).
__global__ __launch_bounds__(1024, 4) void kproj(const float* __restrict__ v,
        const float* __restrict__ w1, const float* __restrict__ b1,
        const float* __restrict__ w2, const float* __restrict__ b2,
        float* __restrict__ out) {
    __shared__ __align__(16) float U[2][8][256];     // 16 KB
    __shared__ __align__(16) float red[16][256];     // 16 KB
    int t = threadIdx.x;
    int b = blockIdx.y;
    int n0 = blockIdx.x * 256;   // 32 blocks x 256 = 8192 exact
    int lane = t & 63;
    int wvu = __builtin_amdgcn_readfirstlane(t >> 6);   // 0..15
    const float* vb = v + (size_t)b * (W * SROW);
    int colf = n0 + lane * 4;
    int h0 = wvu * 8;

    if (wvu < 8) gld16(vb + (size_t)wvu * SROW + colf, &U[0][wvu][0]);

    float acc[8][4];
    #pragma unroll
    for (int r = 0; r < 8; r++) {
        float bs = b1[h0 + r];                      // uniform -> s_load
        acc[r][0] = acc[r][1] = acc[r][2] = acc[r][3] = bs;
    }
    __syncthreads();

    int buf = 0;
    for (int c = 0; c < 8; c++) {
        if (c < 7 && wvu < 8)
            gld16(vb + (size_t)((c + 1) * 8 + wvu) * SROW + colf, &U[buf ^ 1][wvu][0]);
        #pragma unroll
        for (int kk = 0; kk < 8; kk++) {
            int k = c * 8 + kk;
            float4 u = *(const float4*)&U[buf][kk][lane * 4];
            const float* wk = w1 + k * 128 + h0;    // uniform -> s_load
            #pragma unroll
            for (int r = 0; r < 8; r++) {
                float wr = wk[r];
                acc[r][0] = fmaf(wr, u.x, acc[r][0]);
                acc[r][1] = fmaf(wr, u.y, acc[r][1]);
                acc[r][2] = fmaf(wr, u.z, acc[r][2]);
                acc[r][3] = fmaf(wr, u.w, acc[r][3]);
            }
        }
        if (c < 7) { __syncthreads(); buf ^= 1; }
    }

    float p0 = 0.f, p1 = 0.f, p2 = 0.f, p3 = 0.f;
    #pragma unroll
    for (int r = 0; r < 8; r++) {
        float wh = w2[h0 + r];                      // uniform -> s_load
        p0 = fmaf(gelu_exact(acc[r][0]), wh, p0);
        p1 = fmaf(gelu_exact(acc[r][1]), wh, p1);
        p2 = fmaf(gelu_exact(acc[r][2]), wh, p2);
        p3 = fmaf(gelu_exact(acc[r][3]), wh, p3);
    }
    float4 p4 = {p0, p1, p2, p3};
    *(float4*)&red[wvu][lane * 4] = p4;
    __syncthreads();
    if (t < 256) {
        float s = b2[0];
        #pragma unroll
        for (int w = 0; w < 16; w++) s += red[w][t];
        out[(size_t)b * 8192 + n0 + t] = s;
    }
}

extern "C" void kernel_launch(void* const* d_in, const int* in_sizes, int n_in,
                              void* d_out, int out_size, void* d_ws, size_t ws_size,
                              hipStream_t stream) {
    const float* x  = (const float*)d_in[0];
    const float* lw = (const float*)d_in[1];
    const float* lb = (const float*)d_in[2];
    const float* kr = (const float*)d_in[3];
    const float* ki = (const float*)d_in[4];
    const float* cw = (const float*)d_in[5];
    const float* cb = (const float*)d_in[6];
    const float* w1 = (const float*)d_in[7];
    const float* b1 = (const float*)d_in[8];
    const float* w2 = (const float*)d_in[9];
    const float* b2 = (const float*)d_in[10];
    float* out = (float*)d_out;

    // workspace (floats): v 33,619,968 | cosT/sinT 131,328 ea | onesz 24,624 |
    // F 131,072 | Wf 393,216  => ~137.8 MB
    float* ws = (float*)d_ws;
    size_t vsz = (size_t)NB * W * SROW;
    float* v     = ws;
    float* cosT  = v + vsz;
    float* sinT  = cosT + (size_t)16 * SROW;
    float* onesz = sinT + (size_t)16 * SROW;
    float* F     = onesz + (size_t)3 * SROW;
    float* Wf    = F + (size_t)NB * W * M * 2;

    ktable<<<dim3(33, 18), 256, 0, stream>>>(cosT, sinT, onesz);
    klift<<<dim3(9, NB), 256, 0, stream>>>(x, lw, lb, v);

    for (int l = 0; l < NL; l++) {
        kdft<<<NB * W / 2, 256, 0, stream>>>(v, cosT, sinT, F);
        kmix<<<dim3(NB, 4), 256, 0, stream>>>(F, kr, ki, cw, cb, Wf, l);
        kconv<<<dim3(33, NB), 512, 0, stream>>>(v, Wf, cosT, sinT, onesz);
    }
    kproj<<<dim3(32, NB), 1024, 0, stream>>>(v, w1, b1, w2, b2, out);
}

// Round 10
// 1008.438 us; speedup vs baseline: 1.5330x; 1.3599x over previous
//
#include <hip/hip_runtime.h>
#include <math.h>

// FNO1d: B=64, N=8192, F_IN=2, W=64, L=5, M=16, PAD=9 -> NLEN=8201
#define SROW 8224      // row stride: 8224*4 = 32896 B, 128B-aligned rows
#define NLEN 8201
#define NB 64
#define W 64
#define M 16
#define NL 5
#define TWO_PI 6.283185307179586476925286766559

// Branchless gelu: A&S 7.1.26 erf (|err| <= 1.5e-7), rcp+exp2 fast paths.
__device__ __forceinline__ float gelu_f(float x) {
    float s = x * 0.70710678118654752f;
    float a = fabsf(s);
    float t = __builtin_amdgcn_rcpf(fmaf(0.3275911f, a, 1.0f));
    float p = fmaf(1.061405429f, t, -1.453152027f);
    p = fmaf(p, t, 1.421413741f);
    p = fmaf(p, t, -0.284496736f);
    p = fmaf(p, t, 0.254829592f);
    p = p * t;
    float e = __expf(-a * a);
    float er = copysignf(fmaf(-p, e, 1.0f), s);
    float h = 0.5f * x;
    return fmaf(h, er, h);
}

// async global->LDS, 16B per lane: LDS dest = wave-uniform base + lane*16.
__device__ __forceinline__ void gld16(const float* g, float* l) {
    __builtin_amdgcn_global_load_lds(
        (const __attribute__((address_space(1))) void*)g,
        (__attribute__((address_space(3))) void*)l, 16, 0, 0);
}

// Twiddle tables cosT[k][n], sinT[k][n] (fp64-accurate) + ones/zeros rows.
__global__ void ktable(float* __restrict__ cosT, float* __restrict__ sinT,
                       float* __restrict__ onesz) {
    int n = blockIdx.x * 256 + threadIdx.x;
    int k = blockIdx.y;
    if (n >= SROW) return;
    if (k < 16) {
        long long m = ((long long)k * (long long)n) % NLEN;
        double th = (TWO_PI / (double)NLEN) * (double)m;
        double sv, cv;
        sincos(th, &sv, &cv);
        cosT[k * SROW + n] = (float)cv;
        sinT[k * SROW + n] = (float)sv;
    } else {
        onesz[(k - 16) * SROW + n] = (k == 16) ? 1.0f : 0.0f;
    }
}

// Lift: v[b][w][n] = x[b][n][:]@lift_w + lift_b, 0 in pad. 4 cols/thread, float4 I/O.
__global__ __launch_bounds__(256) void klift(const float* __restrict__ x,
        const float* __restrict__ lw, const float* __restrict__ lb,
        float* __restrict__ v) {
    int n4 = blockIdx.x * 256 + threadIdx.x;   // 2056 groups of 4 cols (8224)
    int b = blockIdx.y;
    if (n4 >= 2056) return;
    int n = n4 * 4;
    bool in = (n < 8192);      // 8192%4==0: group fully in or fully pad
    float4 xa = {0.f, 0.f, 0.f, 0.f}, xb = {0.f, 0.f, 0.f, 0.f};
    if (in) {
        const float* xp = x + ((size_t)b * 8192 + n) * 2;
        xa = *(const float4*)xp;       // x0[n],x1[n],x0[n+1],x1[n+1]
        xb = *(const float4*)(xp + 4);
    }
    float* vp = v + (size_t)b * W * SROW + n;
    #pragma unroll
    for (int w = 0; w < W; w++) {
        float4 o4 = {0.f, 0.f, 0.f, 0.f};
        if (in) {
            float l0 = lw[w], l1 = lw[W + w], bb = lb[w];
            o4.x = fmaf(xa.x, l0, fmaf(xa.y, l1, bb));
            o4.y = fmaf(xa.z, l0, fmaf(xa.w, l1, bb));
            o4.z = fmaf(xb.x, l0, fmaf(xb.y, l1, bb));
            o4.w = fmaf(xb.z, l0, fmaf(xb.w, l1, bb));
        }
        *(float4*)(vp + (size_t)w * SROW) = o4;
    }
}

// Forward DFT, 16 modes. 2 rows/block (2048 blocks), LOW-VGPR strided loop:
// acc = 64 regs; twiddles via k-recurrence. Latency hidden by wave count.
__global__ __launch_bounds__(256) void kdft(const float* __restrict__ v,
        const float* __restrict__ cosT, const float* __restrict__ sinT,
        float* __restrict__ F) {
    int row0 = blockIdx.x * 2;
    int t = threadIdx.x;
    float accR[2][16], accI[2][16];
    #pragma unroll
    for (int r = 0; r < 2; r++)
        #pragma unroll
        for (int k = 0; k < 16; k++) { accR[r][k] = 0.f; accI[r][k] = 0.f; }
    const float* v0 = v + (size_t)row0 * SROW;

    for (int c = t; c < 2050; c += 256) {   // n = 4c..4c+3, covers n<8200
        int n = c << 2;
        float4 c1 = *(const float4*)(cosT + SROW + n);
        float4 s1 = *(const float4*)(sinT + SROW + n);
        float4 va = *(const float4*)(v0 + n);
        float4 vb = *(const float4*)(v0 + SROW + n);
        accR[0][0] += (va.x + va.y) + (va.z + va.w);
        accR[1][0] += (vb.x + vb.y) + (vb.z + vb.w);
        float4 ck = c1, sk = s1;
        #pragma unroll
        for (int k = 1; k < 16; k++) {
            float a0 = accR[0][k];
            a0 = fmaf(va.x, ck.x, a0); a0 = fmaf(va.y, ck.y, a0);
            a0 = fmaf(va.z, ck.z, a0); a0 = fmaf(va.w, ck.w, a0);
            accR[0][k] = a0;
            float b0 = accI[0][k];
            b0 = fmaf(-va.x, sk.x, b0); b0 = fmaf(-va.y, sk.y, b0);
            b0 = fmaf(-va.z, sk.z, b0); b0 = fmaf(-va.w, sk.w, b0);
            accI[0][k] = b0;
            float a1 = accR[1][k];
            a1 = fmaf(vb.x, ck.x, a1); a1 = fmaf(vb.y, ck.y, a1);
            a1 = fmaf(vb.z, ck.z, a1); a1 = fmaf(vb.w, ck.w, a1);
            accR[1][k] = a1;
            float b1 = accI[1][k];
            b1 = fmaf(-vb.x, sk.x, b1); b1 = fmaf(-vb.y, sk.y, b1);
            b1 = fmaf(-vb.z, sk.z, b1); b1 = fmaf(-vb.w, sk.w, b1);
            accI[1][k] = b1;
            if (k < 15) {
                float4 cn, sn;
                cn.x = fmaf(ck.x, c1.x, -sk.x * s1.x); sn.x = fmaf(ck.x, s1.x, sk.x * c1.x);
                cn.y = fmaf(ck.y, c1.y, -sk.y * s1.y); sn.y = fmaf(ck.y, s1.y, sk.y * c1.y);
                cn.z = fmaf(ck.z, c1.z, -sk.z * s1.z); sn.z = fmaf(ck.z, s1.z, sk.z * c1.z);
                cn.w = fmaf(ck.w, c1.w, -sk.w * s1.w); sn.w = fmaf(ck.w, s1.w, sk.w * c1.w);
                ck = cn; sk = sn;
            }
        }
    }

    if (t == 0) {        // tail n = 8200 (pad cols beyond 8200 are never read)
        int n = 8200;
        #pragma unroll
        for (int k = 0; k < 16; k++) {
            float cv = cosT[(size_t)k * SROW + n], sv = sinT[(size_t)k * SROW + n];
            float v0r = v0[n], v1r = v0[SROW + n];
            accR[0][k] = fmaf(v0r, cv, accR[0][k]);
            accI[0][k] = fmaf(-v0r, sv, accI[0][k]);
            accR[1][k] = fmaf(v1r, cv, accR[1][k]);
            accI[1][k] = fmaf(-v1r, sv, accI[1][k]);
        }
    }

    #pragma unroll
    for (int r = 0; r < 2; r++)
        #pragma unroll
        for (int k = 0; k < 16; k++) {
            float xr = accR[r][k], xi = accI[r][k];
            #pragma unroll
            for (int off = 32; off > 0; off >>= 1) {
                xr += __shfl_down(xr, off, 64);
                xi += __shfl_down(xi, off, 64);
            }
            accR[r][k] = xr; accI[r][k] = xi;
        }
    __shared__ float red[4][64];
    int lane = t & 63, wv = t >> 6;
    if (lane == 0) {
        #pragma unroll
        for (int r = 0; r < 2; r++)
            #pragma unroll
            for (int k = 0; k < 16; k++) {
                red[wv][r * 32 + 2 * k]     = accR[r][k];
                red[wv][r * 32 + 2 * k + 1] = accI[r][k];
            }
    }
    __syncthreads();
    if (t < 64) {
        float sum = red[0][t] + red[1][t] + red[2][t] + red[3][t];
        int r = t >> 5, rem = t & 31, k = rem >> 1, comp = rem & 1;
        F[(((size_t)(row0 + r)) * M + k) * 2 + comp] = sum;
    }
}

// Mode mix + weight build. Block (b,kg) owns k in [4kg,4kg+4) for all o.
// Wf[b][96][64]: k<64 cw; 64..78 +PmR(1..15)*2/N; 79..93 -PmI(1..15)*2/N;
// 94 cb+PmR(0)/N; 95 zero.
__global__ __launch_bounds__(256) void kmix(const float* __restrict__ F,
        const float* __restrict__ kr, const float* __restrict__ ki,
        const float* __restrict__ cw, const float* __restrict__ cb,
        float* __restrict__ Wf, int l) {
    int b = blockIdx.x, kg = blockIdx.y;
    int t = threadIdx.x;
    int o = t & 63, ii = t >> 6;   // 4 i-groups of 16
    const float* fb = F + (size_t)b * W * M * 2;
    const float* krl = kr + (size_t)l * W * W * M;
    const float* kil = ki + (size_t)l * W * W * M;
    float* wb = Wf + (size_t)b * 96 * 64;
    float pr[4] = {0.f, 0.f, 0.f, 0.f}, pi[4] = {0.f, 0.f, 0.f, 0.f};
    for (int i = ii * 16; i < ii * 16 + 16; i++) {
        float4 kr4 = *(const float4*)(krl + ((size_t)i * W + o) * M + kg * 4);
        float4 ki4 = *(const float4*)(kil + ((size_t)i * W + o) * M + kg * 4);
        float4 f0 = *(const float4*)(fb + ((size_t)i * M + kg * 4) * 2);
        float4 f1 = *(const float4*)(fb + ((size_t)i * M + kg * 4) * 2 + 4);
        pr[0] += f0.x * kr4.x - f0.y * ki4.x;  pi[0] += f0.x * ki4.x + f0.y * kr4.x;
        pr[1] += f0.z * kr4.y - f0.w * ki4.y;  pi[1] += f0.z * ki4.y + f0.w * kr4.y;
        pr[2] += f1.x * kr4.z - f1.y * ki4.z;  pi[2] += f1.x * ki4.z + f1.y * kr4.z;
        pr[3] += f1.z * kr4.w - f1.w * ki4.w;  pi[3] += f1.z * ki4.w + f1.w * kr4.w;
    }
    const float* cwl = cw + (size_t)l * W * W;
    #pragma unroll
    for (int it = 0; it < 4; it++) {
        int idx = t + it * 256;
        int krow = 16 * kg + (idx >> 6), oo = idx & 63;
        wb[krow * 64 + oo] = cwl[oo * 64 + krow];
    }
    __shared__ float red[4][64][8];
    #pragma unroll
    for (int c = 0; c < 4; c++) {
        red[ii][o][2 * c]     = pr[c];
        red[ii][o][2 * c + 1] = pi[c];
    }
    __syncthreads();
    if (ii == 0) {
        #pragma unroll
        for (int c = 0; c < 4; c++) {
            int k = kg * 4 + c;
            float sr = red[0][o][2 * c] + red[1][o][2 * c] + red[2][o][2 * c] + red[3][o][2 * c];
            float si = red[0][o][2 * c + 1] + red[1][o][2 * c + 1] + red[2][o][2 * c + 1] + red[3][o][2 * c + 1];
            if (k == 0) {
                wb[94 * 64 + o] = cb[l * W + o] + sr * (1.0f / (float)NLEN);
                wb[95 * 64 + o] = 0.f;
            } else {
                wb[(63 + k) * 64 + o] = sr * (2.0f / (float)NLEN);
                wb[(78 + k) * 64 + o] = -si * (2.0f / (float)NLEN);
            }
        }
    }
}

// Fused conv + inverse transform + gelu, IN-PLACE. 512 threads = 8 waves.
// Wave w owns o rows [8w,8w+8); block covers 64o x 256n. Thread: 8o x 4n.
// Weights wave-uniform from Wf -> s_load. 8 waves/EU -> 4 blocks/CU (32 waves).
__global__ __launch_bounds__(512, 8) void kconv(float* v,
        const float* __restrict__ Wf, const float* __restrict__ cosT,
        const float* __restrict__ sinT, const float* __restrict__ onesz) {
    __shared__ __align__(16) float U[2][12][256];
    int t = threadIdx.x;
    int b = blockIdx.y;
    int n0 = blockIdx.x * 256;
    int lane = t & 63;
    int wvu = __builtin_amdgcn_readfirstlane(t >> 6);   // 0..7, provably uniform
    const float* vb = v + (size_t)b * (W * SROW);
    const float* Wb = Wf + (size_t)b * (96 * 64) + wvu * 8;
    int colf = n0 + lane * 4;

    // stage chunk 0 (rows 0..11, all v rows)
    gld16(vb + (size_t)wvu * SROW + colf, &U[0][wvu][0]);
    if (wvu < 4) gld16(vb + (size_t)(8 + wvu) * SROW + colf, &U[0][8 + wvu][0]);

    float acc[8][4];
    #pragma unroll
    for (int r = 0; r < 8; r++) { acc[r][0] = acc[r][1] = acc[r][2] = acc[r][3] = 0.f; }
    __syncthreads();

    int buf = 0;
    for (int c = 0; c < 8; c++) {
        if (c < 7) {
            int k0 = (c + 1) * 12;
            int r0 = k0 + wvu;
            const float* s0 = (r0 < 64) ? vb + (size_t)r0 * SROW
                            : (r0 < 79) ? cosT + (size_t)(r0 - 63) * SROW
                            : (r0 < 94) ? sinT + (size_t)(r0 - 78) * SROW
                            : onesz + (size_t)(r0 - 94) * SROW;
            gld16(s0 + colf, &U[buf ^ 1][wvu][0]);
            if (wvu < 4) {
                int r1 = k0 + 8 + wvu;
                const float* s1 = (r1 < 64) ? vb + (size_t)r1 * SROW
                                : (r1 < 79) ? cosT + (size_t)(r1 - 63) * SROW
                                : (r1 < 94) ? sinT + (size_t)(r1 - 78) * SROW
                                : onesz + (size_t)(r1 - 94) * SROW;
                gld16(s1 + colf, &U[buf ^ 1][8 + wvu][0]);
            }
        }
        #pragma unroll
        for (int kk = 0; kk < 12; kk++) {
            int k = c * 12 + kk;
            float4 u = *(const float4*)&U[buf][kk][lane * 4];
            const float* wk = Wb + k * 64;          // wave-uniform -> s_load
            #pragma unroll
            for (int r = 0; r < 8; r++) {
                float wr = wk[r];
                acc[r][0] = fmaf(wr, u.x, acc[r][0]);
                acc[r][1] = fmaf(wr, u.y, acc[r][1]);
                acc[r][2] = fmaf(wr, u.z, acc[r][2]);
                acc[r][3] = fmaf(wr, u.w, acc[r][3]);
            }
        }
        if (c < 7) { __syncthreads(); buf ^= 1; }
    }

    if (colf < SROW) {
        float* vo = v + (size_t)b * (W * SROW) + colf;
        #pragma unroll
        for (int r = 0; r < 8; r++) {
            float4 o4;
            o4.x = gelu_f(acc[r][0]);
            o4.y = gelu_f(acc[r][1]);
            o4.z = gelu_f(acc[r][2]);
            o4.w = gelu_f(acc[r][3]);
            *(float4*)(vo + (size_t)(wvu * 8 + r) * SROW) = o4;
        }
    }
}

// Final projection: 1024 threads = 16 waves; wave w owns h rows [8w,8w+8)
// (weights wave-uniform -> s_load); thread tile 8h x 4n (acc=32 regs).
// 8 waves/EU requested -> 2 blocks/CU if VGPR stays <= 64.
__global__ __launch_bounds__(1024, 8) void kproj(const float* __restrict__ v,
        const float* __restrict__ w1, const float* __restrict__ b1,
        const float* __restrict__ w2, const float* __restrict__ b2,
        float* __restrict__ out) {
    __shared__ __align__(16) float U[2][8][256];     // 16 KB
    __shared__ __align__(16) float red[16][256];     // 16 KB
    int t = threadIdx.x;
    int b = blockIdx.y;
    int n0 = blockIdx.x * 256;   // 32 blocks x 256 = 8192 exact
    int lane = t & 63;
    int wvu = __builtin_amdgcn_readfirstlane(t >> 6);   // 0..15
    const float* vb = v + (size_t)b * (W * SROW);
    int colf = n0 + lane * 4;
    int h0 = wvu * 8;

    if (wvu < 8) gld16(vb + (size_t)wvu * SROW + colf, &U[0][wvu][0]);

    float acc[8][4];
    #pragma unroll
    for (int r = 0; r < 8; r++) {
        float bs = b1[h0 + r];                      // uniform -> s_load
        acc[r][0] = acc[r][1] = acc[r][2] = acc[r][3] = bs;
    }
    __syncthreads();

    int buf = 0;
    for (int c = 0; c < 8; c++) {
        if (c < 7 && wvu < 8)
            gld16(vb + (size_t)((c + 1) * 8 + wvu) * SROW + colf, &U[buf ^ 1][wvu][0]);
        #pragma unroll
        for (int kk = 0; kk < 8; kk++) {
            int k = c * 8 + kk;
            float4 u = *(const float4*)&U[buf][kk][lane * 4];
            const float* wk = w1 + k * 128 + h0;    // uniform -> s_load
            #pragma unroll
            for (int r = 0; r < 8; r++) {
                float wr = wk[r];
                acc[r][0] = fmaf(wr, u.x, acc[r][0]);
                acc[r][1] = fmaf(wr, u.y, acc[r][1]);
                acc[r][2] = fmaf(wr, u.z, acc[r][2]);
                acc[r][3] = fmaf(wr, u.w, acc[r][3]);
            }
        }
        if (c < 7) { __syncthreads(); buf ^= 1; }
    }

    float p0 = 0.f, p1 = 0.f, p2 = 0.f, p3 = 0.f;
    #pragma unroll
    for (int r = 0; r < 8; r++) {
        float wh = w2[h0 + r];                      // uniform -> s_load
        p0 = fmaf(gelu_f(acc[r][0]), wh, p0);
        p1 = fmaf(gelu_f(acc[r][1]), wh, p1);
        p2 = fmaf(gelu_f(acc[r][2]), wh, p2);
        p3 = fmaf(gelu_f(acc[r][3]), wh, p3);
    }
    float4 p4 = {p0, p1, p2, p3};
    *(float4*)&red[wvu][lane * 4] = p4;
    __syncthreads();
    if (t < 256) {
        float s = b2[0];
        #pragma unroll
        for (int w = 0; w < 16; w++) s += red[w][t];
        out[(size_t)b * 8192 + n0 + t] = s;
    }
}

extern "C" void kernel_launch(void* const* d_in, const int* in_sizes, int n_in,
                              void* d_out, int out_size, void* d_ws, size_t ws_size,
                              hipStream_t stream) {
    const float* x  = (const float*)d_in[0];
    const float* lw = (const float*)d_in[1];
    const float* lb = (const float*)d_in[2];
    const float* kr = (const float*)d_in[3];
    const float* ki = (const float*)d_in[4];
    const float* cw = (const float*)d_in[5];
    const float* cb = (const float*)d_in[6];
    const float* w1 = (const float*)d_in[7];
    const float* b1 = (const float*)d_in[8];
    const float* w2 = (const float*)d_in[9];
    const float* b2 = (const float*)d_in[10];
    float* out = (float*)d_out;

    // workspace (floats): v 33,685,504 | cosT/sinT 131,584 ea | onesz 24,672 |
    // F 131,072 | Wf 393,216  => ~138.0 MB
    float* ws = (float*)d_ws;
    size_t vsz = (size_t)NB * W * SROW;
    float* v     = ws;
    float* cosT  = v + vsz;
    float* sinT  = cosT + (size_t)16 * SROW;
    float* onesz = sinT + (size_t)16 * SROW;
    float* F     = onesz + (size_t)3 * SROW;
    float* Wf    = F + (size_t)NB * W * M * 2;

    ktable<<<dim3(33, 18), 256, 0, stream>>>(cosT, sinT, onesz);
    klift<<<dim3(9, NB), 256, 0, stream>>>(x, lw, lb, v);

    for (int l = 0; l < NL; l++) {
        kdft<<<NB * W / 2, 256, 0, stream>>>(v, cosT, sinT, F);
        kmix<<<dim3(NB, 4), 256, 0, stream>>>(F, kr, ki, cw, cb, Wf, l);
        kconv<<<dim3(33, NB), 512, 0, stream>>>(v, Wf, cosT, sinT, onesz);
    }
    kproj<<<dim3(32, NB), 1024, 0, stream>>>(v, w1, b1, w2, b2, out);
}